// Round 3
// baseline (452.274 us; speedup 1.0000x reference)
//
#include <hip/hip_runtime.h>

#define D 96

// ---------------- CSR build ----------------

__global__ void count_kernel(const int* __restrict__ ei, int* __restrict__ cnt, int e) {
    int i = blockIdx.x * 256 + threadIdx.x;
    if (i < e) atomicAdd(&cnt[ei[e + i]], 1);   // dst row of edge_index
}

__global__ void scan_blocks(const int* __restrict__ cnt, int* __restrict__ rp,
                            int* __restrict__ bsums, int n) {
    __shared__ int s[256];
    int i = blockIdx.x * 256 + threadIdx.x;
    int v = (i < n) ? cnt[i] : 0;
    s[threadIdx.x] = v;
    __syncthreads();
    for (int off = 1; off < 256; off <<= 1) {
        int t = (threadIdx.x >= off) ? s[threadIdx.x - off] : 0;
        __syncthreads();
        s[threadIdx.x] += t;
        __syncthreads();
    }
    if (i < n) rp[i] = s[threadIdx.x] - v;          // exclusive within block
    if (threadIdx.x == 255) bsums[blockIdx.x] = s[255];
}

__global__ void scan_sums(int* __restrict__ bsums, int nb) {
    __shared__ int s[512];
    int t = threadIdx.x;
    int v = (t < nb) ? bsums[t] : 0;
    s[t] = v;
    __syncthreads();
    for (int off = 1; off < 512; off <<= 1) {
        int u = (t >= off) ? s[t - off] : 0;
        __syncthreads();
        s[t] += u;
        __syncthreads();
    }
    if (t < nb) bsums[t] = s[t] - v;                // exclusive block offsets
}

__global__ void add_offsets(int* __restrict__ rp, const int* __restrict__ bsums, int n) {
    int i = blockIdx.x * 256 + threadIdx.x;
    if (i < n) rp[i] += bsums[blockIdx.x];
}

__global__ void dis_kernel(const int* __restrict__ cnt, float* __restrict__ dis,
                           int n, int* __restrict__ rp, int e) {
    int i = blockIdx.x * 256 + threadIdx.x;
    if (i < n) dis[i] = rsqrtf((float)(cnt[i] + 1));   // +1 self-loop
    if (i == 0) rp[n] = e;
}

__global__ void scatter_kernel(const int* __restrict__ ei, int* __restrict__ fill,
                               const int* __restrict__ rp, int* __restrict__ esrc, int e) {
    int i = blockIdx.x * 256 + threadIdx.x;
    if (i < e) {
        int d = ei[e + i];                 // dst
        int pos = rp[d] + atomicAdd(&fill[d], 1);
        esrc[pos] = ei[i];                 // src
    }
}

// ---------------- hs = dis[row] * (X @ W) ----------------
// 128 threads: 64 rows x 96 cols per block; 8x6 register tile per thread.
// All LDS compute reads are ds_read_b128 along k (ws transposed; xs k4-swizzled).
// LDS pool (64000 B < 64 KiB): ws_t 96x100 floats | regionA 64x100 floats
//   regionA first holds a 48x97 W row-chunk (transpose staging), then the X tile.

#define XS_S 100   // xs row stride in floats (400B, 16B-aligned blocks)
#define WT_S 100   // ws_t row stride in floats

__global__ __launch_bounds__(128) void gemm_scale(const float* __restrict__ X,
                                                  const float* __restrict__ W,
                                                  const float* __restrict__ dis,
                                                  float* __restrict__ out, int n) {
    __shared__ float lds[9600 + 6400];
    float* ws_t = lds;            // [96][WT_S] : ws_t[c][k] = W[k][c]
    float* regA = lds + 9600;     // chunk buffer, then xs [64][XS_S]
    int t = threadIdx.x;
    int row0 = blockIdx.x * 64;

    // ---- build ws_t in two 48-row chunks (48x97 fits regionA) ----
    #pragma unroll
    for (int chunk = 0; chunk < 2; ++chunk) {
        int kbase = chunk * 48;
        for (int i = t; i < 48 * 96; i += 128) {
            int k = i / 96, c = i % 96;
            regA[k * 97 + c] = W[(kbase + k) * 96 + c];   // coalesced
        }
        __syncthreads();
        for (int idx = t; idx < 96 * 12; idx += 128) {
            int c = idx / 12, k4 = idx % 12;              // k4 local to chunk
            float4 v;
            v.x = regA[(k4 * 4 + 0) * 97 + c];
            v.y = regA[(k4 * 4 + 1) * 97 + c];
            v.z = regA[(k4 * 4 + 2) * 97 + c];
            v.w = regA[(k4 * 4 + 3) * 97 + c];
            *(float4*)&ws_t[c * WT_S + (kbase / 4 + k4) * 4] = v;
        }
        __syncthreads();
    }

    // ---- stage X tile (k4-block XOR swizzle keyed by r>>3) ----
    for (int i = t; i < 64 * 24; i += 128) {
        int r = i / 24, c4 = i % 24;
        int gr = row0 + r;
        float4 v = (gr < n) ? ((const float4*)(X + (size_t)gr * D))[c4]
                            : make_float4(0.f, 0.f, 0.f, 0.f);
        *(float4*)&regA[r * XS_S + 4 * (c4 ^ ((r >> 3) & 7))] = v;
    }
    __syncthreads();

    int rg = t & 7;       // rows rg*8 .. +7
    int cg = t >> 3;      // cols cg*6 .. +5
    float acc[8][6] = {};
    for (int k4 = 0; k4 < 24; ++k4) {
        float4 a[8], b[6];
        int xk = 4 * (k4 ^ rg);            // swizzled k4-block (rg == r>>3 for all 8 rows)
        #pragma unroll
        for (int i = 0; i < 8; ++i)
            a[i] = *(const float4*)&regA[(rg * 8 + i) * XS_S + xk];
        #pragma unroll
        for (int j = 0; j < 6; ++j)
            b[j] = *(const float4*)&ws_t[(cg * 6 + j) * WT_S + k4 * 4];
        #pragma unroll
        for (int i = 0; i < 8; ++i)
            #pragma unroll
            for (int j = 0; j < 6; ++j) {
                acc[i][j] += a[i].x * b[j].x;
                acc[i][j] += a[i].y * b[j].y;
                acc[i][j] += a[i].z * b[j].z;
                acc[i][j] += a[i].w * b[j].w;
            }
    }
    #pragma unroll
    for (int i = 0; i < 8; ++i) {
        int gr = row0 + rg * 8 + i;
        if (gr < n) {
            float dsc = dis[gr];
            #pragma unroll
            for (int j = 0; j < 6; ++j)
                out[(size_t)gr * D + cg * 6 + j] = dsc * acc[i][j];
        }
    }
}

// ---------------- out = relu(dis[i]*(hs[i] + sum_{e:dst=i} hs[src]) + b) ----------------
// 32 lanes per node, 3 floats per lane (32*12B = one 384B row).

__global__ __launch_bounds__(256) void agg_kernel(const float* __restrict__ hs,
                                                  const float* __restrict__ dis,
                                                  const float* __restrict__ bias,
                                                  const int* __restrict__ rp,
                                                  const int* __restrict__ esrc,
                                                  float* __restrict__ out, int n) {
    int lane = threadIdx.x & 31;
    int node = blockIdx.x * 8 + (threadIdx.x >> 5);
    if (node >= n) return;
    int c = lane * 3;
    const float* base = hs + (size_t)node * D + c;
    float a0 = base[0], a1 = base[1], a2 = base[2];   // self-loop term
    int beg = rp[node], end = rp[node + 1];
    for (int e = beg; e < end; ++e) {
        const float* p = hs + (size_t)esrc[e] * D + c;
        a0 += p[0]; a1 += p[1]; a2 += p[2];
    }
    float dsc = dis[node];
    float* o = out + (size_t)node * D + c;
    o[0] = fmaxf(dsc * a0 + bias[c + 0], 0.f);
    o[1] = fmaxf(dsc * a1 + bias[c + 1], 0.f);
    o[2] = fmaxf(dsc * a2 + bias[c + 2], 0.f);
}

extern "C" void kernel_launch(void* const* d_in, const int* in_sizes, int n_in,
                              void* d_out, int out_size, void* d_ws, size_t ws_size,
                              hipStream_t stream) {
    const float* x  = (const float*)d_in[0];
    const int*   ei = (const int*)d_in[1];
    const float* W1 = (const float*)d_in[2];
    const float* b1 = (const float*)d_in[3];
    const float* W2 = (const float*)d_in[4];
    const float* b2 = (const float*)d_in[5];
    float* out = (float*)d_out;
    int n = in_sizes[0] / D;
    int e = in_sizes[1] / 2;

    char* ws = (char*)d_ws;
    size_t off = 0;
    auto take = [&](size_t bytes) {
        char* p = ws + off;
        off += (bytes + 511) & ~511ULL;
        return p;
    };
    int*   cnt   = (int*)take((size_t)n * 4);
    int*   rp    = (int*)take((size_t)(n + 1) * 4);
    int*   fill  = (int*)take((size_t)n * 4);
    int*   bsums = (int*)take(512 * 4);
    float* dsc   = (float*)take((size_t)n * 4);
    int*   esrc  = (int*)take((size_t)e * 4);
    float* A     = (float*)take((size_t)n * D * 4);
    float* B     = (float*)take((size_t)n * D * 4);

    hipMemsetAsync(cnt, 0, (size_t)n * 4, stream);
    hipMemsetAsync(fill, 0, (size_t)n * 4, stream);

    int nbE = (e + 255) / 256;
    int nbN = (n + 255) / 256;
    count_kernel<<<nbE, 256, 0, stream>>>(ei, cnt, e);
    scan_blocks<<<nbN, 256, 0, stream>>>(cnt, rp, bsums, n);
    scan_sums<<<1, 512, 0, stream>>>(bsums, nbN);
    add_offsets<<<nbN, 256, 0, stream>>>(rp, bsums, n);
    dis_kernel<<<nbN, 256, 0, stream>>>(cnt, dsc, n, rp, e);
    scatter_kernel<<<nbE, 256, 0, stream>>>(ei, fill, rp, esrc, e);

    int nbG = (n + 63) / 64;
    gemm_scale<<<nbG, 128, 0, stream>>>(x, W1, dsc, A, n);
    agg_kernel<<<(n + 7) / 8, 256, 0, stream>>>(A, dsc, b1, rp, esrc, B, n);
    gemm_scale<<<nbG, 128, 0, stream>>>(B, W2, dsc, A, n);
    agg_kernel<<<(n + 7) / 8, 256, 0, stream>>>(A, dsc, b2, rp, esrc, out, n);
}

// Round 8
// 371.891 us; speedup vs baseline: 1.2161x; 1.2161x over previous
//
#include <hip/hip_runtime.h>

#define D 96

// ---------------- CSR build ----------------

__global__ void count_kernel(const int* __restrict__ ei, int* __restrict__ cnt, int e) {
    int i = blockIdx.x * 256 + threadIdx.x;
    if (i < e) atomicAdd(&cnt[ei[e + i]], 1);   // dst row of edge_index
}

__global__ void scan_blocks(const int* __restrict__ cnt, int* __restrict__ rp,
                            int* __restrict__ bsums, int n) {
    __shared__ int s[256];
    int i = blockIdx.x * 256 + threadIdx.x;
    int v = (i < n) ? cnt[i] : 0;
    s[threadIdx.x] = v;
    __syncthreads();
    for (int off = 1; off < 256; off <<= 1) {
        int t = (threadIdx.x >= off) ? s[threadIdx.x - off] : 0;
        __syncthreads();
        s[threadIdx.x] += t;
        __syncthreads();
    }
    if (i < n) rp[i] = s[threadIdx.x] - v;          // exclusive within block
    if (threadIdx.x == 255) bsums[blockIdx.x] = s[255];
}

__global__ void scan_sums(int* __restrict__ bsums, int nb) {
    __shared__ int s[512];
    int t = threadIdx.x;
    int v = (t < nb) ? bsums[t] : 0;
    s[t] = v;
    __syncthreads();
    for (int off = 1; off < 512; off <<= 1) {
        int u = (t >= off) ? s[t - off] : 0;
        __syncthreads();
        s[t] += u;
        __syncthreads();
    }
    if (t < nb) bsums[t] = s[t] - v;                // exclusive block offsets
}

__global__ void add_offsets(int* __restrict__ rp, const int* __restrict__ bsums, int n) {
    int i = blockIdx.x * 256 + threadIdx.x;
    if (i < n) rp[i] += bsums[blockIdx.x];
}

__global__ void dis_kernel(const int* __restrict__ cnt, float* __restrict__ dis,
                           int n, int* __restrict__ rp, int e) {
    int i = blockIdx.x * 256 + threadIdx.x;
    if (i < n) dis[i] = rsqrtf((float)(cnt[i] + 1));   // +1 self-loop
    if (i == 0) rp[n] = e;
}

__global__ void scatter_kernel(const int* __restrict__ ei, int* __restrict__ fill,
                               const int* __restrict__ rp, int* __restrict__ esrc, int e) {
    int i = blockIdx.x * 256 + threadIdx.x;
    if (i < e) {
        int d = ei[e + i];                 // dst
        int pos = rp[d] + atomicAdd(&fill[d], 1);
        esrc[pos] = ei[i];                 // src
    }
}

// ---------------- one-shot W transpose: Wt[c][k] = W[k][c] ----------------

__global__ void wt_kernel(const float* __restrict__ W1, const float* __restrict__ W2,
                          float* __restrict__ Wt1, float* __restrict__ Wt2) {
    int i = blockIdx.x * 256 + threadIdx.x;
    if (i < D * D) {
        int k = i / D, c = i % D;
        Wt1[c * D + k] = W1[i];
        Wt2[c * D + k] = W2[i];
    }
}

// ---------------- hs = dis[row] * (X @ W) ----------------
// 256 threads: 128 rows x 96 cols per block; 8x6 register tile per thread.
// K chunked by 32 -> LDS 32256 B/block -> 4 blocks/CU (VGPR-capped at 128 by
// __launch_bounds__(256,4)) = 16 waves/CU. All compute reads ds_read_b128.
// Swizzle audit: a-reads 2-way bank alias (free, m136); b-reads banks {0,24,16,8}.

#define KC 32
#define XS_S 36
#define WT_S 36

__global__ __launch_bounds__(256, 4) void gemm_scale(const float* __restrict__ X,
                                                     const float* __restrict__ Wt,
                                                     const float* __restrict__ dis,
                                                     float* __restrict__ out, int n) {
    __shared__ float xs[128 * XS_S];   // 18432 B
    __shared__ float wt[96 * WT_S];    // 13824 B
    int t = threadIdx.x;
    int row0 = blockIdx.x * 128;
    int rg = t & 15;      // rows rg*8 .. +7
    int cg = t >> 4;      // cols cg*6 .. +5
    float acc[8][6] = {};

    for (int kc = 0; kc < D; kc += KC) {
        for (int i = t; i < 96 * 8; i += 256) {            // wt chunk
            int c = i >> 3, c4 = i & 7;
            float4 v = *(const float4*)&Wt[c * D + kc + c4 * 4];
            *(float4*)&wt[c * WT_S + c4 * 4] = v;
        }
        for (int i = t; i < 128 * 8; i += 256) {           // xs chunk (swizzled)
            int r = i >> 3, c4 = i & 7;
            int gr = row0 + r;
            float4 v = (gr < n) ? *(const float4*)&X[(size_t)gr * D + kc + c4 * 4]
                                : make_float4(0.f, 0.f, 0.f, 0.f);
            *(float4*)&xs[r * XS_S + 4 * (c4 ^ ((r >> 3) & 7))] = v;
        }
        __syncthreads();
        #pragma unroll
        for (int k4 = 0; k4 < 8; ++k4) {
            float4 a[8], b[6];
            int xk = 4 * (k4 ^ (rg & 7));
            #pragma unroll
            for (int i = 0; i < 8; ++i)
                a[i] = *(const float4*)&xs[(rg * 8 + i) * XS_S + xk];
            #pragma unroll
            for (int j = 0; j < 6; ++j)
                b[j] = *(const float4*)&wt[(cg * 6 + j) * WT_S + k4 * 4];
            #pragma unroll
            for (int i = 0; i < 8; ++i)
                #pragma unroll
                for (int j = 0; j < 6; ++j) {
                    acc[i][j] += a[i].x * b[j].x;
                    acc[i][j] += a[i].y * b[j].y;
                    acc[i][j] += a[i].z * b[j].z;
                    acc[i][j] += a[i].w * b[j].w;
                }
        }
        __syncthreads();
    }
    #pragma unroll
    for (int i = 0; i < 8; ++i) {
        int gr = row0 + rg * 8 + i;
        if (gr < n) {
            float dsc = dis[gr];
            #pragma unroll
            for (int j = 0; j < 6; ++j)
                out[(size_t)gr * D + cg * 6 + j] = dsc * acc[i][j];
        }
    }
}

// ---------------- out = relu(dis[i]*(hs[i] + sum_{e:dst=i} hs[src]) + b) ----------------
// 24 active lanes per 32-lane node-group, one float4 per lane (24*16B = 384B row).
// 2-way edge unroll with dual accumulators for memory-level parallelism.

__global__ __launch_bounds__(256) void agg_kernel(const float* __restrict__ hs,
                                                  const float* __restrict__ dis,
                                                  const float* __restrict__ bias,
                                                  const int* __restrict__ rp,
                                                  const int* __restrict__ esrc,
                                                  float* __restrict__ out, int n) {
    int lane = threadIdx.x & 31;
    int node = blockIdx.x * 8 + (threadIdx.x >> 5);
    if (node >= n || lane >= 24) return;
    float4 s = ((const float4*)(hs + (size_t)node * D))[lane];   // self-loop term
    float4 s2 = make_float4(0.f, 0.f, 0.f, 0.f);
    int beg = rp[node], end = rp[node + 1];
    int e = beg;
    for (; e + 1 < end; e += 2) {
        float4 v0 = ((const float4*)(hs + (size_t)esrc[e] * D))[lane];
        float4 v1 = ((const float4*)(hs + (size_t)esrc[e + 1] * D))[lane];
        s.x += v0.x;  s.y += v0.y;  s.z += v0.z;  s.w += v0.w;
        s2.x += v1.x; s2.y += v1.y; s2.z += v1.z; s2.w += v1.w;
    }
    if (e < end) {
        float4 v0 = ((const float4*)(hs + (size_t)esrc[e] * D))[lane];
        s.x += v0.x; s.y += v0.y; s.z += v0.z; s.w += v0.w;
    }
    float dsc = dis[node];
    float4 b = ((const float4*)bias)[lane];
    float4 o;
    o.x = fmaxf(dsc * (s.x + s2.x) + b.x, 0.f);
    o.y = fmaxf(dsc * (s.y + s2.y) + b.y, 0.f);
    o.z = fmaxf(dsc * (s.z + s2.z) + b.z, 0.f);
    o.w = fmaxf(dsc * (s.w + s2.w) + b.w, 0.f);
    ((float4*)(out + (size_t)node * D))[lane] = o;
}

extern "C" void kernel_launch(void* const* d_in, const int* in_sizes, int n_in,
                              void* d_out, int out_size, void* d_ws, size_t ws_size,
                              hipStream_t stream) {
    const float* x  = (const float*)d_in[0];
    const int*   ei = (const int*)d_in[1];
    const float* W1 = (const float*)d_in[2];
    const float* b1 = (const float*)d_in[3];
    const float* W2 = (const float*)d_in[4];
    const float* b2 = (const float*)d_in[5];
    float* out = (float*)d_out;
    int n = in_sizes[0] / D;
    int e = in_sizes[1] / 2;

    char* ws = (char*)d_ws;
    size_t off = 0;
    auto take = [&](size_t bytes) {
        char* p = ws + off;
        off += (bytes + 511) & ~511ULL;
        return p;
    };
    int*   cnt   = (int*)take((size_t)n * 4);
    int*   rp    = (int*)take((size_t)(n + 1) * 4);
    int*   fill  = (int*)take((size_t)n * 4);
    int*   bsums = (int*)take(512 * 4);
    float* dsc   = (float*)take((size_t)n * 4);
    float* Wt1   = (float*)take((size_t)D * D * 4);
    float* Wt2   = (float*)take((size_t)D * D * 4);
    int*   esrc  = (int*)take((size_t)e * 4);
    float* A     = (float*)take((size_t)n * D * 4);
    float* B     = (float*)take((size_t)n * D * 4);

    hipMemsetAsync(cnt, 0, (size_t)n * 4, stream);
    hipMemsetAsync(fill, 0, (size_t)n * 4, stream);

    int nbE = (e + 255) / 256;
    int nbN = (n + 255) / 256;
    count_kernel<<<nbE, 256, 0, stream>>>(ei, cnt, e);
    scan_blocks<<<nbN, 256, 0, stream>>>(cnt, rp, bsums, n);
    scan_sums<<<1, 512, 0, stream>>>(bsums, nbN);
    add_offsets<<<nbN, 256, 0, stream>>>(rp, bsums, n);
    dis_kernel<<<nbN, 256, 0, stream>>>(cnt, dsc, n, rp, e);
    scatter_kernel<<<nbE, 256, 0, stream>>>(ei, fill, rp, esrc, e);
    wt_kernel<<<(2 * D * D + 255) / 256, 256, 0, stream>>>(W1, W2, Wt1, Wt2);

    int nbG = (n + 127) / 128;
    gemm_scale<<<nbG, 256, 0, stream>>>(x, Wt1, dsc, A, n);
    agg_kernel<<<(n + 7) / 8, 256, 0, stream>>>(A, dsc, b1, rp, esrc, B, n);
    gemm_scale<<<nbG, 256, 0, stream>>>(B, Wt2, dsc, A, n);
    agg_kernel<<<(n + 7) / 8, 256, 0, stream>>>(A, dsc, b2, rp, esrc, out, n);
}